// Round 10
// baseline (299.706 us; speedup 1.0000x reference)
//
#include <hip/hip_runtime.h>

#define IN_C 128
#define HID_C 64
#define OUT_C 32
#define NBLK 512    // edge blocks for bucket partition
#define NBUCK 512   // buckets = node>>8 (391 used for n=100000)
#define CAP 5120    // fixed bucket capacity: mean 4096 + 16 sigma

typedef unsigned int uint;
typedef unsigned short ushort;
typedef __attribute__((ext_vector_type(8))) short bf16x8;
typedef __attribute__((ext_vector_type(4))) float f32x4;

__device__ __forceinline__ uint bf16pair(float a, float b) {
  uint ua = __float_as_uint(a), ub = __float_as_uint(b);
  ua = (ua + 0x7FFFu + ((ua >> 16) & 1u)) >> 16;
  ub = (ub + 0x7FFFu + ((ub >> 16) & 1u)) >> 16;
  return ua | (ub << 16);
}

__device__ __forceinline__ uint bf16one(float a) {
  uint u = __float_as_uint(a);
  return (u + 0x7FFFu + ((u >> 16) & 1u)) >> 16;
}

// Accumulate 8 bf16 feats (one dwordx4) into 8 f32 accumulators.
__device__ __forceinline__ void acc8(float* acc, uint4 q) {
  acc[0] += __uint_as_float(q.x << 16);
  acc[1] += __uint_as_float(q.x & 0xFFFF0000u);
  acc[2] += __uint_as_float(q.y << 16);
  acc[3] += __uint_as_float(q.y & 0xFFFF0000u);
  acc[4] += __uint_as_float(q.z << 16);
  acc[5] += __uint_as_float(q.z & 0xFFFF0000u);
  acc[6] += __uint_as_float(q.w << 16);
  acc[7] += __uint_as_float(q.w & 0xFFFF0000u);
}

// ---------- CSR build ----------

__global__ void __launch_bounds__(256) scatter_reserve_kernel(
    const int* __restrict__ row, const int* __restrict__ col,
    int* __restrict__ gcur, int* __restrict__ ebuf, int e, int epb) {
  __shared__ int hist[NBUCK];
  __shared__ int cur[NBUCK];
  int t = threadIdx.x, b = blockIdx.x;
  for (int i = t; i < NBUCK; i += 256) hist[i] = 0;
  __syncthreads();
  int s = b * epb, en = min(e, s + epb);
  for (int i = s + t; i < en; i += 256) atomicAdd(&hist[col[i] >> 8], 1);
  __syncthreads();
  for (int i = t; i < NBUCK; i += 256) {
    int h = hist[i];
    int base = h ? atomicAdd(&gcur[i], h) : 0;
    cur[i] = CAP * i + base;
  }
  __syncthreads();
  for (int i = s + t; i < en; i += 256) {
    int c = col[i], r = row[i];
    int bk = c >> 8;
    int p = atomicAdd(&cur[bk], 1);
    if (p < CAP * bk + CAP) ebuf[p] = r | ((c & 255) << 17);  // n < 2^17
  }
}

// 1024-key (target-in-bucket x source-quarter) count + scan + regroup.
// offQ[node*5+q] = segment start of (node, quarter q); [node*5+4] = end.
// srt entries stored relative to source-HALF base (fits ushort).
__global__ void __launch_bounds__(256) csr_kernel(const int* __restrict__ ebuf,
                                                  const int* __restrict__ gcur,
                                                  int* __restrict__ offQ,
                                                  ushort* __restrict__ srt,
                                                  float* __restrict__ dinv,
                                                  int n, int qb) {
  __shared__ int cnt[1024];
  __shared__ int bsum[256];
  int t = threadIdx.x, b = blockIdx.x;
  int es = b * CAP;
  int ec = min(gcur[b], CAP);
  for (int i = t; i < 1024; i += 256) cnt[i] = 0;
  __syncthreads();
  for (int i = t; i < ec; i += 256) {
    int pv = ebuf[es + i];
    int r = pv & 0x1FFFF;
    int q = (r >= qb) + (r >= 2 * qb) + (r >= 3 * qb);
    atomicAdd(&cnt[(((pv >> 17) & 255) << 2) | q], 1);
  }
  __syncthreads();
  int c0 = cnt[t * 4], c1 = cnt[t * 4 + 1], c2 = cnt[t * 4 + 2], c3 = cnt[t * 4 + 3];
  int tot = c0 + c1 + c2 + c3;
  bsum[t] = tot;
  __syncthreads();
  for (int d = 1; d < 256; d <<= 1) {
    int a = (t >= d) ? bsum[t - d] : 0;
    __syncthreads();
    bsum[t] += a;
    __syncthreads();
  }
  int g0 = es + bsum[t] - tot;
  int g1 = g0 + c0, g2 = g1 + c1, g3 = g2 + c2, g4 = g3 + c3;
  int node = b * 256 + t;
  if (node < n) {
    offQ[node * 5 + 0] = g0;
    offQ[node * 5 + 1] = g1;
    offQ[node * 5 + 2] = g2;
    offQ[node * 5 + 3] = g3;
    offQ[node * 5 + 4] = g4;
    dinv[node] = rsqrtf((float)(tot + 1));
  }
  cnt[t * 4] = g0; cnt[t * 4 + 1] = g1; cnt[t * 4 + 2] = g2; cnt[t * 4 + 3] = g3;
  __syncthreads();
  for (int i = t; i < ec; i += 256) {
    int pv = ebuf[es + i];
    int r = pv & 0x1FFFF;
    int q = (r >= qb) + (r >= 2 * qb) + (r >= 3 * qb);
    int key = (((pv >> 17) & 255) << 2) | q;
    int pos = atomicAdd(&cnt[key], 1);
    srt[pos] = (ushort)(r - (q >> 1) * (2 * qb));  // half-relative (< 2*qb <= 65536)
  }
}

// ---------- weight prep (bf16 hi/lo splits, transposed) ----------

__global__ void __launch_bounds__(256) prep_w_kernel(const float* __restrict__ W1,
                                                     const float* __restrict__ W2,
                                                     ushort* __restrict__ w1t_hi,
                                                     ushort* __restrict__ w1t_lo,
                                                     ushort* __restrict__ w2t_hi,
                                                     ushort* __restrict__ w2t_lo) {
  int t = threadIdx.x;
  for (int i = t; i < HID_C * IN_C; i += 256) {
    int c = i >> 7, k = i & 127;
    float v = W1[k * HID_C + c];
    uint h = bf16one(v);
    float lo = v - __uint_as_float(h << 16);
    w1t_hi[i] = (ushort)h;
    w1t_lo[i] = (ushort)bf16one(lo);
  }
  for (int i = t; i < OUT_C * HID_C; i += 256) {
    int c = i >> 6, k = i & 63;
    float v = W2[k * OUT_C + c];
    uint h = bf16one(v);
    float lo = v - __uint_as_float(h << 16);
    w2t_hi[i] = (ushort)h;
    w2t_lo[i] = (ushort)bf16one(lo);
  }
}

// ---------- gemm1 via split-bf16 MFMA, LDS-transposed coalesced store ----------
// xw1b[r][64] = bf16((x[r,:] @ W1) * dinv[r]).  64 rows/block.
#define APAD 136   // ushort stride for staging
#define EPAD 68    // f32 stride for epilogue (68%4==0 -> aligned b128)
__global__ void __launch_bounds__(256) gemm1_mfma_kernel(
    const float* __restrict__ x, const ushort* __restrict__ w1t_hi,
    const ushort* __restrict__ w1t_lo, const float* __restrict__ dinv,
    ushort* __restrict__ xw1b, int n) {
  __shared__ ushort xs_hi[64 * APAD];   // 17408 B (reused as 64*EPAD f32 epilogue)
  __shared__ ushort xs_lo[64 * APAD];
  __shared__ float dinv_s[64];
  int t = threadIdx.x;
  int row0 = blockIdx.x * 64;
  if (t < 64) {
    int rr = row0 + t;
    dinv_s[t] = rr < n ? dinv[rr] : 0.f;
  }
  for (int task = t; task < 64 * 16; task += 256) {
    int r = task >> 4, kc = task & 15;
    int grow = row0 + r;
    uint4 hq = {0u, 0u, 0u, 0u}, lq = {0u, 0u, 0u, 0u};
    if (grow < n) {
      const float* xp = x + (size_t)grow * IN_C + kc * 8;
      float4 v0 = *(const float4*)xp;
      float4 v1 = *(const float4*)(xp + 4);
      float vv[8] = {v0.x, v0.y, v0.z, v0.w, v1.x, v1.y, v1.z, v1.w};
      uint hu[8];
      float lf[8];
#pragma unroll
      for (int i = 0; i < 8; ++i) {
        hu[i] = bf16one(vv[i]);
        lf[i] = vv[i] - __uint_as_float(hu[i] << 16);
      }
      hq = make_uint4(hu[0] | (hu[1] << 16), hu[2] | (hu[3] << 16),
                      hu[4] | (hu[5] << 16), hu[6] | (hu[7] << 16));
      lq = make_uint4(bf16pair(lf[0], lf[1]), bf16pair(lf[2], lf[3]),
                      bf16pair(lf[4], lf[5]), bf16pair(lf[6], lf[7]));
    }
    *(uint4*)(xs_hi + r * APAD + kc * 8) = hq;
    *(uint4*)(xs_lo + r * APAD + kc * 8) = lq;
  }
  __syncthreads();
  int wv = t >> 6, lane = t & 63, m = lane & 15, q = lane >> 4;
  f32x4 acc[4];
#pragma unroll
  for (int ct = 0; ct < 4; ++ct) acc[ct] = (f32x4){0.f, 0.f, 0.f, 0.f};
  const ushort* ah_p = xs_hi + (wv * 16 + m) * APAD + q * 8;
  const ushort* al_p = xs_lo + (wv * 16 + m) * APAD + q * 8;
#pragma unroll
  for (int kb = 0; kb < 4; ++kb) {
    bf16x8 ah = *(const bf16x8*)(ah_p + kb * 32);
    bf16x8 al = *(const bf16x8*)(al_p + kb * 32);
#pragma unroll
    for (int ct = 0; ct < 4; ++ct) {
      const ushort* bp = w1t_hi + (ct * 16 + m) * IN_C + kb * 32 + q * 8;
      bf16x8 bh = *(const bf16x8*)bp;
      bf16x8 bl = *(const bf16x8*)(bp + (size_t)(w1t_lo - w1t_hi));
      acc[ct] = __builtin_amdgcn_mfma_f32_16x16x32_bf16(ah, bh, acc[ct], 0, 0, 0);
      acc[ct] = __builtin_amdgcn_mfma_f32_16x16x32_bf16(al, bh, acc[ct], 0, 0, 0);
      acc[ct] = __builtin_amdgcn_mfma_f32_16x16x32_bf16(ah, bl, acc[ct], 0, 0, 0);
    }
  }
  // Epilogue: LDS f32 transpose -> coalesced uint2 stores.
  __syncthreads();
  float* eps = (float*)xs_hi;  // 64 x EPAD
#pragma unroll
  for (int ct = 0; ct < 4; ++ct)
#pragma unroll
    for (int rg = 0; rg < 4; ++rg)
      eps[(wv * 16 + q * 4 + rg) * EPAD + ct * 16 + m] = acc[ct][rg];
  __syncthreads();
  for (int task = t; task < 64 * 16; task += 256) {
    int r = task >> 4, cc = task & 15;
    int grow = row0 + r;
    if (grow < n) {
      float4 v = *(const float4*)&eps[r * EPAD + cc * 4];
      float dv = dinv_s[r];
      uint2 o = make_uint2(bf16pair(v.x * dv, v.y * dv), bf16pair(v.z * dv, v.w * dv));
      ((uint2*)(xw1b + (size_t)grow * HID_C))[cc] = o;
    }
  }
}

// ---------- gather1: source-quartered partial sums (XCD-pinned slices) ----------
// bid -> q=bid&3, fh=(bid>>2)&1, chunk=bid>>3: the 8 (q,fh) combos map 1:1 to XCDs.
// 64 nodes/block, 4-lane group per node, lane = 16 B of the 64 B feat-half row.
__global__ void __launch_bounds__(256) gather1_q_kernel(
    const int* __restrict__ offQ, const ushort* __restrict__ srt,
    const ushort* __restrict__ xw1b, ushort* __restrict__ pacc1,
    int base, int rowEnd, int prows, int qb) {
  int t = threadIdx.x, bid = blockIdx.x;
  int q = bid & 3, fh = (bid >> 2) & 1, chunk = bid >> 3;
  int g = t >> 2, fl = t & 3;
  int c = base + chunk * 64 + g;
  if (c >= rowEnd) return;
  int js = offQ[c * 5 + q], je = offQ[c * 5 + q + 1];
  int rbase = (q >> 1) * (2 * qb);
  const uint4* tbl = (const uint4*)xw1b;  // row r = 8 uint4; half fh at +fh*4
  int sel = fh * 4 + fl;
  float a[8] = {0.f, 0.f, 0.f, 0.f, 0.f, 0.f, 0.f, 0.f};
  float b[8] = {0.f, 0.f, 0.f, 0.f, 0.f, 0.f, 0.f, 0.f};
  int j = js;
  for (; j + 3 < je; j += 4) {
    int r0 = (int)__builtin_nontemporal_load(srt + j) + rbase;
    int r1 = (int)__builtin_nontemporal_load(srt + j + 1) + rbase;
    int r2 = (int)__builtin_nontemporal_load(srt + j + 2) + rbase;
    int r3 = (int)__builtin_nontemporal_load(srt + j + 3) + rbase;
    acc8(a, tbl[(size_t)r0 * 8 + sel]);
    acc8(b, tbl[(size_t)r1 * 8 + sel]);
    acc8(a, tbl[(size_t)r2 * 8 + sel]);
    acc8(b, tbl[(size_t)r3 * 8 + sel]);
  }
  for (; j < je; ++j) {
    int r = (int)__builtin_nontemporal_load(srt + j) + rbase;
    acc8(a, tbl[(size_t)r * 8 + sel]);
  }
  uint4 o = make_uint4(bf16pair(a[0] + b[0], a[1] + b[1]),
                       bf16pair(a[2] + b[2], a[3] + b[3]),
                       bf16pair(a[4] + b[4], a[5] + b[5]),
                       bf16pair(a[6] + b[6], a[7] + b[7]));
  *(uint4*)(pacc1 + ((size_t)(q * 2 + fh) * prows + (c - base)) * 32 + fl * 8) = o;
}

// ---------- gemm2 via MFMA with folded combine + LDS-transposed store ----------
// A-frag: h = relu((sum4 partials + self) * dinv + b1), built from streamed reads.
#define EPAD2 36
__global__ void __launch_bounds__(256) gemm2_mfma_kernel(
    const ushort* __restrict__ pacc1, const ushort* __restrict__ xw1b,
    const float* __restrict__ b1, const ushort* __restrict__ w2t_hi,
    const ushort* __restrict__ w2t_lo, const float* __restrict__ dinv,
    ushort* __restrict__ hw2b, int base, int rowEnd, int prows) {
  __shared__ float eps[64 * EPAD2];  // 9216 B
  int t = threadIdx.x;
  int wv = t >> 6, lane = t & 63, m = lane & 15, q = lane >> 4;
  int rblk = base + blockIdx.x * 64;
  int arow = min(rblk + wv * 16 + m, rowEnd - 1);
  float dv_a = dinv[arow];
  bf16x8 afr[2];
#pragma unroll
  for (int part = 0; part < 2; ++part) {
    float s[8] = {0.f, 0.f, 0.f, 0.f, 0.f, 0.f, 0.f, 0.f};
    acc8(s, ((const uint4*)xw1b)[(size_t)arow * 8 + part * 4 + q]);  // self
#pragma unroll
    for (int qq = 0; qq < 4; ++qq)
      acc8(s, ((const uint4*)pacc1)[((size_t)(qq * 2 + part) * prows + (arow - base)) * 4 + q]);
    float4 bb0 = ((const float4*)b1)[part * 8 + q * 2];
    float4 bb1 = ((const float4*)b1)[part * 8 + q * 2 + 1];
    float h[8];
    h[0] = s[0] * dv_a + bb0.x; h[1] = s[1] * dv_a + bb0.y;
    h[2] = s[2] * dv_a + bb0.z; h[3] = s[3] * dv_a + bb0.w;
    h[4] = s[4] * dv_a + bb1.x; h[5] = s[5] * dv_a + bb1.y;
    h[6] = s[6] * dv_a + bb1.z; h[7] = s[7] * dv_a + bb1.w;
#pragma unroll
    for (int i = 0; i < 8; ++i) h[i] = h[i] > 0.f ? h[i] : 0.f;
    uint4 u = make_uint4(bf16pair(h[0], h[1]), bf16pair(h[2], h[3]),
                         bf16pair(h[4], h[5]), bf16pair(h[6], h[7]));
    afr[part] = *(bf16x8*)&u;
  }
  f32x4 acc[2];
  acc[0] = (f32x4){0.f, 0.f, 0.f, 0.f};
  acc[1] = (f32x4){0.f, 0.f, 0.f, 0.f};
#pragma unroll
  for (int ct = 0; ct < 2; ++ct) {
    const ushort* bp = w2t_hi + (ct * 16 + m) * HID_C + q * 8;
    const ushort* blp = w2t_lo + (ct * 16 + m) * HID_C + q * 8;
    bf16x8 bh0 = *(const bf16x8*)bp;
    bf16x8 bh1 = *(const bf16x8*)(bp + 32);
    bf16x8 bl0 = *(const bf16x8*)blp;
    bf16x8 bl1 = *(const bf16x8*)(blp + 32);
    acc[ct] = __builtin_amdgcn_mfma_f32_16x16x32_bf16(afr[0], bh0, acc[ct], 0, 0, 0);
    acc[ct] = __builtin_amdgcn_mfma_f32_16x16x32_bf16(afr[1], bh1, acc[ct], 0, 0, 0);
    acc[ct] = __builtin_amdgcn_mfma_f32_16x16x32_bf16(afr[0], bl0, acc[ct], 0, 0, 0);
    acc[ct] = __builtin_amdgcn_mfma_f32_16x16x32_bf16(afr[1], bl1, acc[ct], 0, 0, 0);
  }
  // Epilogue: LDS f32 transpose -> coalesced uint2 stores (scaled by dinv).
#pragma unroll
  for (int ct = 0; ct < 2; ++ct)
#pragma unroll
    for (int rg = 0; rg < 4; ++rg)
      eps[(wv * 16 + q * 4 + rg) * EPAD2 + ct * 16 + m] = acc[ct][rg];
  __syncthreads();
  for (int task = t; task < 64 * 8; task += 256) {
    int r = task >> 3, cc = task & 7;
    int node = rblk + r;
    if (node < rowEnd) {
      float4 v = *(const float4*)&eps[r * EPAD2 + cc * 4];
      float dv = dinv[node];
      uint2 o = make_uint2(bf16pair(v.x * dv, v.y * dv), bf16pair(v.z * dv, v.w * dv));
      ((uint2*)(hw2b + (size_t)node * OUT_C))[cc] = o;
    }
  }
}

// ---------- gather2: source-halved partial sums (XCD-pinned slices) ----------
// 64 nodes/block, 4-lane group per node, lane = 16 B of the 64 B row.
__global__ void __launch_bounds__(256) gather2_h_kernel(
    const int* __restrict__ offQ, const ushort* __restrict__ srt,
    const ushort* __restrict__ hw2b, ushort* __restrict__ pacc2, int n, int qb) {
  int t = threadIdx.x, bid = blockIdx.x;
  int q2 = bid & 1, chunk = bid >> 1;
  int g = t >> 2, fl = t & 3;
  int c = chunk * 64 + g;
  if (c >= n) return;
  int js = offQ[c * 5 + 2 * q2], je = offQ[c * 5 + 2 * q2 + 2];
  int rbase = q2 * 2 * qb;
  const uint4* tbl = (const uint4*)hw2b;  // row r = 4 uint4
  float a[8] = {0.f, 0.f, 0.f, 0.f, 0.f, 0.f, 0.f, 0.f};
  float b[8] = {0.f, 0.f, 0.f, 0.f, 0.f, 0.f, 0.f, 0.f};
  int j = js;
  for (; j + 3 < je; j += 4) {
    int r0 = (int)__builtin_nontemporal_load(srt + j) + rbase;
    int r1 = (int)__builtin_nontemporal_load(srt + j + 1) + rbase;
    int r2 = (int)__builtin_nontemporal_load(srt + j + 2) + rbase;
    int r3 = (int)__builtin_nontemporal_load(srt + j + 3) + rbase;
    acc8(a, tbl[(size_t)r0 * 4 + fl]);
    acc8(b, tbl[(size_t)r1 * 4 + fl]);
    acc8(a, tbl[(size_t)r2 * 4 + fl]);
    acc8(b, tbl[(size_t)r3 * 4 + fl]);
  }
  for (; j < je; ++j) {
    int r = (int)__builtin_nontemporal_load(srt + j) + rbase;
    acc8(a, tbl[(size_t)r * 4 + fl]);
  }
  uint4 o = make_uint4(bf16pair(a[0] + b[0], a[1] + b[1]),
                       bf16pair(a[2] + b[2], a[3] + b[3]),
                       bf16pair(a[4] + b[4], a[5] + b[5]),
                       bf16pair(a[6] + b[6], a[7] + b[7]));
  *(uint4*)(pacc2 + ((size_t)q2 * n + c) * 32 + fl * 8) = o;
}

// combine2: out = (pacc2[0] + pacc2[1] + self) * dinv + b2  (f32 output).
__global__ void __launch_bounds__(256) combine2_kernel(
    const ushort* __restrict__ pacc2, const ushort* __restrict__ hw2b,
    const float* __restrict__ dinv, const float* __restrict__ b2,
    float* __restrict__ out, int n) {
  int idx = blockIdx.x * 256 + threadIdx.x;
  if (idx >= n * 16) return;
  int c = idx >> 4, d = idx & 15;
  uint p0 = ((const uint*)pacc2)[(size_t)c * 16 + d];
  uint p1 = ((const uint*)pacc2)[((size_t)n + c) * 16 + d];
  uint sf = ((const uint*)hw2b)[(size_t)c * 16 + d];
  float dv = dinv[c];
  float2 bb = ((const float2*)b2)[d];
  float2 o;
  o.x = (__uint_as_float(p0 << 16) + __uint_as_float(p1 << 16) +
         __uint_as_float(sf << 16)) * dv + bb.x;
  o.y = (__uint_as_float(p0 & 0xFFFF0000u) + __uint_as_float(p1 & 0xFFFF0000u) +
         __uint_as_float(sf & 0xFFFF0000u)) * dv + bb.y;
  ((float2*)out)[idx] = o;
}

extern "C" void kernel_launch(void* const* d_in, const int* in_sizes, int n_in,
                              void* d_out, int out_size, void* d_ws, size_t ws_size,
                              hipStream_t stream) {
  const float* x  = (const float*)d_in[0];
  const int*   ei = (const int*)d_in[1];
  const float* W1 = (const float*)d_in[2];
  const float* b1 = (const float*)d_in[3];
  const float* W2 = (const float*)d_in[4];
  const float* b2 = (const float*)d_in[5];
  float* out = (float*)d_out;

  int n = in_sizes[0] / IN_C;  // 100000
  int e = in_sizes[1] / 2;     // 1600000
  const int* row = ei;         // sources
  const int* col = ei + e;     // targets
  int qb = (n + 3) / 4;        // 25000 source-quarter size
  int half = n / 2;            // 50000 target-pass size

  // workspace layout (~53 MB):
  //   ebuf aliases pacc1 (ebuf dead after csr; pacc1 written by gather1)
  //   pacc2 aliases xw1b (xw1b last read by gemm2 pass B; gather2 runs after)
  float*  dinv  = (float*)d_ws;                          // n
  int*    offQ  = (int*)(dinv + n);                      // n*5
  int*    gcur  = offQ + (size_t)n * 5;                  // NBUCK
  ushort* srt   = (ushort*)(gcur + NBUCK);               // NBUCK*CAP ushort (5.25MB)
  ushort* xw1b  = srt + (size_t)NBUCK * CAP;             // n*64 bf16 (12.8MB)
  ushort* pacc1 = xw1b + (size_t)n * HID_C;              // 8*half*32 bf16 (25.6MB)
  int*    ebuf  = (int*)pacc1;                           // NBUCK*CAP ints (10.5MB), alias
  ushort* hw2b  = pacc1 + (size_t)8 * half * 32;         // n*32 bf16 (6.4MB)
  ushort* pacc2 = xw1b;                                  // 2*n*32 bf16 (12.8MB), alias
  ushort* w1t_hi = hw2b + (size_t)n * OUT_C;             // 64*128
  ushort* w1t_lo = w1t_hi + HID_C * IN_C;
  ushort* w2t_hi = w1t_lo + HID_C * IN_C;
  ushort* w2t_lo = w2t_hi + OUT_C * HID_C;

  int epb = (e + NBLK - 1) / NBLK;                       // 3125
  int nbuckets = (n + 255) / 256;                        // 391
  int ch1 = (half + 63) / 64;                            // 782 chunks per pass
  int ch2 = (n + 63) / 64;                               // 1563

  hipMemsetAsync(gcur, 0, NBUCK * sizeof(int), stream);
  hipLaunchKernelGGL(scatter_reserve_kernel, dim3(NBLK), dim3(256), 0, stream,
                     row, col, gcur, ebuf, e, epb);
  hipLaunchKernelGGL(csr_kernel, dim3(nbuckets), dim3(256), 0, stream,
                     ebuf, gcur, offQ, srt, dinv, n, qb);
  hipLaunchKernelGGL(prep_w_kernel, dim3(1), dim3(256), 0, stream,
                     W1, W2, w1t_hi, w1t_lo, w2t_hi, w2t_lo);
  hipLaunchKernelGGL(gemm1_mfma_kernel, dim3((n + 63) / 64), dim3(256), 0, stream,
                     x, w1t_hi, w1t_lo, dinv, xw1b, n);
  // pass A: targets [0, half)
  hipLaunchKernelGGL(gather1_q_kernel, dim3(ch1 * 8), dim3(256), 0, stream,
                     offQ, srt, xw1b, pacc1, 0, half, half, qb);
  hipLaunchKernelGGL(gemm2_mfma_kernel, dim3(ch1), dim3(256), 0, stream,
                     pacc1, xw1b, b1, w2t_hi, w2t_lo, dinv, hw2b, 0, half, half);
  // pass B: targets [half, n)
  hipLaunchKernelGGL(gather1_q_kernel, dim3(ch1 * 8), dim3(256), 0, stream,
                     offQ, srt, xw1b, pacc1, half, n, half, qb);
  hipLaunchKernelGGL(gemm2_mfma_kernel, dim3(ch1), dim3(256), 0, stream,
                     pacc1, xw1b, b1, w2t_hi, w2t_lo, dinv, hw2b, half, n, half);
  // layer-2 gather (source halves) + combine
  hipLaunchKernelGGL(gather2_h_kernel, dim3(ch2 * 2), dim3(256), 0, stream,
                     offQ, srt, hw2b, pacc2, n, qb);
  hipLaunchKernelGGL(combine2_kernel, dim3((n * 16 + 255) / 256), dim3(256), 0, stream,
                     pacc2, hw2b, dinv, b2, out, n);
}

// Round 11
// 247.315 us; speedup vs baseline: 1.2118x; 1.2118x over previous
//
#include <hip/hip_runtime.h>

#define IN_C 128
#define HID_C 64
#define OUT_C 32
#define NBLK 512    // edge blocks for bucket partition
#define NBUCK 512   // buckets = node>>8 (391 used for n=100000)
#define CAP 5120    // fixed bucket capacity: mean 4096 + 16 sigma

typedef unsigned int uint;
typedef unsigned short ushort;
typedef __attribute__((ext_vector_type(8))) short bf16x8;
typedef __attribute__((ext_vector_type(4))) float f32x4;

__device__ __forceinline__ uint bf16pair(float a, float b) {
  uint ua = __float_as_uint(a), ub = __float_as_uint(b);
  ua = (ua + 0x7FFFu + ((ua >> 16) & 1u)) >> 16;
  ub = (ub + 0x7FFFu + ((ub >> 16) & 1u)) >> 16;
  return ua | (ub << 16);
}

__device__ __forceinline__ uint bf16one(float a) {
  uint u = __float_as_uint(a);
  return (u + 0x7FFFu + ((u >> 16) & 1u)) >> 16;
}

// Accumulate 8 bf16 feats (one dwordx4) into 8 f32 accumulators.
__device__ __forceinline__ void acc8(float* acc, uint4 q) {
  acc[0] += __uint_as_float(q.x << 16);
  acc[1] += __uint_as_float(q.x & 0xFFFF0000u);
  acc[2] += __uint_as_float(q.y << 16);
  acc[3] += __uint_as_float(q.y & 0xFFFF0000u);
  acc[4] += __uint_as_float(q.z << 16);
  acc[5] += __uint_as_float(q.z & 0xFFFF0000u);
  acc[6] += __uint_as_float(q.w << 16);
  acc[7] += __uint_as_float(q.w & 0xFFFF0000u);
}

// ---------- CSR build (R6/R7 verified) ----------

__global__ void __launch_bounds__(256) scatter_reserve_kernel(
    const int* __restrict__ row, const int* __restrict__ col,
    int* __restrict__ gcur, int* __restrict__ ebuf, int e, int epb) {
  __shared__ int hist[NBUCK];
  __shared__ int cur[NBUCK];
  int t = threadIdx.x, b = blockIdx.x;
  for (int i = t; i < NBUCK; i += 256) hist[i] = 0;
  __syncthreads();
  int s = b * epb, en = min(e, s + epb);
  for (int i = s + t; i < en; i += 256) atomicAdd(&hist[col[i] >> 8], 1);
  __syncthreads();
  for (int i = t; i < NBUCK; i += 256) {
    int h = hist[i];
    int base = h ? atomicAdd(&gcur[i], h) : 0;
    cur[i] = CAP * i + base;
  }
  __syncthreads();
  for (int i = s + t; i < en; i += 256) {
    int c = col[i], r = row[i];
    int bk = c >> 8;
    int p = atomicAdd(&cur[bk], 1);
    if (p < CAP * bk + CAP) ebuf[p] = r | ((c & 255) << 17);  // n < 2^17
  }
}

__global__ void __launch_bounds__(256) csr_kernel(const int* __restrict__ ebuf,
                                                  const int* __restrict__ gcur,
                                                  int* __restrict__ offS, int* __restrict__ offE,
                                                  int* __restrict__ srt, float* __restrict__ dinv,
                                                  int n) {
  __shared__ int cnt[256];
  __shared__ int base[256];
  int t = threadIdx.x, b = blockIdx.x;
  int es = b * CAP;
  int ec = min(gcur[b], CAP);
  cnt[t] = 0;
  __syncthreads();
  for (int i = t; i < ec; i += 256) atomicAdd(&cnt[(ebuf[es + i] >> 17) & 255], 1);
  __syncthreads();
  int v = cnt[t];
  base[t] = v;
  __syncthreads();
  for (int d = 1; d < 256; d <<= 1) {
    int a = (t >= d) ? base[t - d] : 0;
    __syncthreads();
    base[t] += a;
    __syncthreads();
  }
  int gstart = es + base[t] - v;
  int node = b * 256 + t;
  if (node < n) {
    offS[node] = gstart;
    offE[node] = gstart + v;
    dinv[node] = rsqrtf((float)(v + 1));
  }
  base[t] = gstart;  // repurpose as cursor
  __syncthreads();
  for (int i = t; i < ec; i += 256) {
    int pv = ebuf[es + i];
    int pos = atomicAdd(&base[(pv >> 17) & 255], 1);
    srt[pos] = pv & 0x1FFFF;
  }
}

// ---------- weight prep (bf16 hi/lo split of W1, transposed) ----------

__global__ void __launch_bounds__(256) prep_w1t_kernel(const float* __restrict__ W1,
                                                       ushort* __restrict__ w1t_hi,
                                                       ushort* __restrict__ w1t_lo) {
  int t = threadIdx.x;
  for (int i = t; i < HID_C * IN_C; i += 256) {
    int c = i >> 7, k = i & 127;
    float v = W1[k * HID_C + c];
    uint h = bf16one(v);
    float lo = v - __uint_as_float(h << 16);
    w1t_hi[i] = (ushort)h;
    w1t_lo[i] = (ushort)bf16one(lo);
  }
}

// ---------- gemm1: barrier-free register MFMA ----------
// xw1b[r][64] = bf16((x[r,:] @ W1) * dinv[r]).  64 rows/block, 4 waves,
// wave = 16 rows. A-fragments loaded straight from global into registers
// (lane m,q -> row m, cols kb*32+q*8), bf16 hi/lo split in-register,
// x*W1 = xh*Wh + xl*Wh + xh*Wl. One barrier; per-wave LDS f32 transpose
// -> coalesced uint4 stores.
__global__ void __launch_bounds__(256) gemm1_mfma_kernel(
    const float* __restrict__ x, const ushort* __restrict__ w1t_hi,
    const ushort* __restrict__ w1t_lo, const float* __restrict__ dinv,
    ushort* __restrict__ xw1b, int n) {
  __shared__ float eps[4][16 * 68];  // 17408 B total
  int t = threadIdx.x;
  int wv = t >> 6, lane = t & 63, m = lane & 15, q = lane >> 4;
  int row0 = blockIdx.x * 64 + wv * 16;
  int arow = min(row0 + m, n - 1);
  const float* xp = x + (size_t)arow * IN_C + q * 8;
  bf16x8 ah[4], al[4];
#pragma unroll
  for (int kb = 0; kb < 4; ++kb) {
    float4 v0 = *(const float4*)(xp + kb * 32);
    float4 v1 = *(const float4*)(xp + kb * 32 + 4);
    float vv[8] = {v0.x, v0.y, v0.z, v0.w, v1.x, v1.y, v1.z, v1.w};
    uint hu[8];
    float lf[8];
#pragma unroll
    for (int i = 0; i < 8; ++i) {
      hu[i] = bf16one(vv[i]);
      lf[i] = vv[i] - __uint_as_float(hu[i] << 16);
    }
    uint4 hq = make_uint4(hu[0] | (hu[1] << 16), hu[2] | (hu[3] << 16),
                          hu[4] | (hu[5] << 16), hu[6] | (hu[7] << 16));
    uint4 lq = make_uint4(bf16pair(lf[0], lf[1]), bf16pair(lf[2], lf[3]),
                          bf16pair(lf[4], lf[5]), bf16pair(lf[6], lf[7]));
    ah[kb] = *(bf16x8*)&hq;
    al[kb] = *(bf16x8*)&lq;
  }
  f32x4 acc[4];
#pragma unroll
  for (int ct = 0; ct < 4; ++ct) acc[ct] = (f32x4){0.f, 0.f, 0.f, 0.f};
#pragma unroll
  for (int kb = 0; kb < 4; ++kb) {
#pragma unroll
    for (int ct = 0; ct < 4; ++ct) {
      const ushort* bp = w1t_hi + (ct * 16 + m) * IN_C + kb * 32 + q * 8;
      bf16x8 bh = *(const bf16x8*)bp;
      bf16x8 bl = *(const bf16x8*)(w1t_lo + (ct * 16 + m) * IN_C + kb * 32 + q * 8);
      acc[ct] = __builtin_amdgcn_mfma_f32_16x16x32_bf16(ah[kb], bh, acc[ct], 0, 0, 0);
      acc[ct] = __builtin_amdgcn_mfma_f32_16x16x32_bf16(al[kb], bh, acc[ct], 0, 0, 0);
      acc[ct] = __builtin_amdgcn_mfma_f32_16x16x32_bf16(ah[kb], bl, acc[ct], 0, 0, 0);
    }
  }
  // Epilogue: per-wave LDS f32 transpose (C/D: col=lane&15, row=q*4+rg).
  float* ep = eps[wv];
#pragma unroll
  for (int ct = 0; ct < 4; ++ct)
#pragma unroll
    for (int rg = 0; rg < 4; ++rg)
      ep[(q * 4 + rg) * 68 + ct * 16 + m] = acc[ct][rg];
  __syncthreads();
#pragma unroll
  for (int it = 0; it < 2; ++it) {
    int r = it * 8 + (lane >> 3), cc = lane & 7;
    int grow = row0 + r;
    if (grow < n) {
      float4 v0 = *(const float4*)&ep[r * 68 + cc * 8];
      float4 v1 = *(const float4*)&ep[r * 68 + cc * 8 + 4];
      float dv = dinv[grow];
      uint4 o = make_uint4(bf16pair(v0.x * dv, v0.y * dv), bf16pair(v0.z * dv, v0.w * dv),
                           bf16pair(v1.x * dv, v1.y * dv), bf16pair(v1.z * dv, v1.w * dv));
      *(uint4*)(xw1b + (size_t)grow * HID_C + cc * 8) = o;
    }
  }
}

// ---------- fused gather1 + relu + gemm2 (R7 verified, 52 us) ----------
// 32 nodes/block; 8-lane group per node, lane = one dwordx4 (8 bf16 feats).
__global__ void __launch_bounds__(256) gather1_gemm2_kernel(
    const int* __restrict__ offS, const int* __restrict__ offE, const int* __restrict__ srt,
    const float* __restrict__ dinv, const ushort* __restrict__ xw1b,
    const float* __restrict__ b1, const float* __restrict__ W2,
    ushort* __restrict__ hw2b, int n) {
  __shared__ float w2s[HID_C * OUT_C];  // 8 KB
  __shared__ float hs[32][HID_C];       // 8 KB
  int t = threadIdx.x;
  for (int i = t; i < HID_C * OUT_C; i += 256) w2s[i] = W2[i];
  int g = t >> 3, fl = t & 7;
  int c = blockIdx.x * 32 + g;
  if (c < n) {
    int js = offS[c], je = offE[c];
    float acc[8] = {0.f, 0.f, 0.f, 0.f, 0.f, 0.f, 0.f, 0.f};
    float acc2[8] = {0.f, 0.f, 0.f, 0.f, 0.f, 0.f, 0.f, 0.f};
    int j = js;
    for (; j + 3 < je; j += 4) {
      int r0 = __builtin_nontemporal_load(srt + j);
      int r1 = __builtin_nontemporal_load(srt + j + 1);
      int r2 = __builtin_nontemporal_load(srt + j + 2);
      int r3 = __builtin_nontemporal_load(srt + j + 3);
      uint4 q0 = ((const uint4*)(xw1b + (size_t)r0 * HID_C))[fl];
      uint4 q1 = ((const uint4*)(xw1b + (size_t)r1 * HID_C))[fl];
      uint4 q2 = ((const uint4*)(xw1b + (size_t)r2 * HID_C))[fl];
      uint4 q3 = ((const uint4*)(xw1b + (size_t)r3 * HID_C))[fl];
      acc8(acc, q0); acc8(acc2, q1); acc8(acc, q2); acc8(acc2, q3);
    }
    for (; j < je; ++j) {
      int r = __builtin_nontemporal_load(srt + j);
      acc8(acc, ((const uint4*)(xw1b + (size_t)r * HID_C))[fl]);
    }
    acc8(acc, ((const uint4*)(xw1b + (size_t)c * HID_C))[fl]);  // self loop
    float dv = dinv[c];
    const float4* b1v = (const float4*)b1;
    float4 blo = b1v[fl * 2], bhi = b1v[fl * 2 + 1];
    float h0 = (acc[0] + acc2[0]) * dv + blo.x;
    float h1 = (acc[1] + acc2[1]) * dv + blo.y;
    float h2 = (acc[2] + acc2[2]) * dv + blo.z;
    float h3 = (acc[3] + acc2[3]) * dv + blo.w;
    float h4 = (acc[4] + acc2[4]) * dv + bhi.x;
    float h5 = (acc[5] + acc2[5]) * dv + bhi.y;
    float h6 = (acc[6] + acc2[6]) * dv + bhi.z;
    float h7 = (acc[7] + acc2[7]) * dv + bhi.w;
    float4 lo = {h0 > 0.f ? h0 : 0.f, h1 > 0.f ? h1 : 0.f,
                 h2 > 0.f ? h2 : 0.f, h3 > 0.f ? h3 : 0.f};
    float4 hi = {h4 > 0.f ? h4 : 0.f, h5 > 0.f ? h5 : 0.f,
                 h6 > 0.f ? h6 : 0.f, h7 > 0.f ? h7 : 0.f};
    ((float4*)hs[g])[fl * 2] = lo;
    ((float4*)hs[g])[fl * 2 + 1] = hi;
  }
  __syncthreads();
  // gemm2 epilogue: 32 nodes x 16 out-pairs = 512 tasks over 256 threads
  for (int task = t; task < 32 * (OUT_C / 2); task += 256) {
    int nl = task >> 4, pr = task & 15;
    int c2 = blockIdx.x * 32 + nl;
    if (c2 < n) {
      float s0 = 0.f, s1 = 0.f;
      const float* hr = hs[nl];
#pragma unroll
      for (int k = 0; k < HID_C; ++k) {
        float hv = hr[k];
        s0 += hv * w2s[k * OUT_C + pr * 2];
        s1 += hv * w2s[k * OUT_C + pr * 2 + 1];
      }
      float dv2 = dinv[c2];
      ((uint*)(hw2b + (size_t)c2 * OUT_C))[pr] = bf16pair(s0 * dv2, s1 * dv2);
    }
  }
}

// ---------- gather2 (R7 verified): 64 nodes/block; 4-lane group per node ----------
__global__ void __launch_bounds__(256) gather2_kernel(
    const int* __restrict__ offS, const int* __restrict__ offE, const int* __restrict__ srt,
    const float* __restrict__ dinv, const ushort* __restrict__ hw2b,
    const float* __restrict__ b2, float* __restrict__ out, int n) {
  int t = threadIdx.x;
  int g = t >> 2, fl = t & 3;
  int c = blockIdx.x * 64 + g;
  if (c >= n) return;
  int js = offS[c], je = offE[c];
  float acc[8] = {0.f, 0.f, 0.f, 0.f, 0.f, 0.f, 0.f, 0.f};
  float acc2[8] = {0.f, 0.f, 0.f, 0.f, 0.f, 0.f, 0.f, 0.f};
  int j = js;
  for (; j + 3 < je; j += 4) {
    int r0 = __builtin_nontemporal_load(srt + j);
    int r1 = __builtin_nontemporal_load(srt + j + 1);
    int r2 = __builtin_nontemporal_load(srt + j + 2);
    int r3 = __builtin_nontemporal_load(srt + j + 3);
    uint4 q0 = ((const uint4*)(hw2b + (size_t)r0 * OUT_C))[fl];
    uint4 q1 = ((const uint4*)(hw2b + (size_t)r1 * OUT_C))[fl];
    uint4 q2 = ((const uint4*)(hw2b + (size_t)r2 * OUT_C))[fl];
    uint4 q3 = ((const uint4*)(hw2b + (size_t)r3 * OUT_C))[fl];
    acc8(acc, q0); acc8(acc2, q1); acc8(acc, q2); acc8(acc2, q3);
  }
  for (; j < je; ++j) {
    int r = __builtin_nontemporal_load(srt + j);
    acc8(acc, ((const uint4*)(hw2b + (size_t)r * OUT_C))[fl]);
  }
  acc8(acc, ((const uint4*)(hw2b + (size_t)c * OUT_C))[fl]);  // self loop
  float dv = dinv[c];
  const float4* b2v = (const float4*)b2;
  float4 blo = b2v[fl * 2], bhi = b2v[fl * 2 + 1];
  float4 olo = {(acc[0] + acc2[0]) * dv + blo.x, (acc[1] + acc2[1]) * dv + blo.y,
                (acc[2] + acc2[2]) * dv + blo.z, (acc[3] + acc2[3]) * dv + blo.w};
  float4 ohi = {(acc[4] + acc2[4]) * dv + bhi.x, (acc[5] + acc2[5]) * dv + bhi.y,
                (acc[6] + acc2[6]) * dv + bhi.z, (acc[7] + acc2[7]) * dv + bhi.w};
  ((float4*)(out + (size_t)c * OUT_C))[fl * 2] = olo;
  ((float4*)(out + (size_t)c * OUT_C))[fl * 2 + 1] = ohi;
}

extern "C" void kernel_launch(void* const* d_in, const int* in_sizes, int n_in,
                              void* d_out, int out_size, void* d_ws, size_t ws_size,
                              hipStream_t stream) {
  const float* x  = (const float*)d_in[0];
  const int*   ei = (const int*)d_in[1];
  const float* W1 = (const float*)d_in[2];
  const float* b1 = (const float*)d_in[3];
  const float* W2 = (const float*)d_in[4];
  const float* b2 = (const float*)d_in[5];
  float* out = (float*)d_out;

  int n = in_sizes[0] / IN_C;  // 100000
  int e = in_sizes[1] / 2;     // 1600000
  const int* row = ei;         // sources
  const int* col = ei + e;     // targets

  // workspace (ebuf aliases xw1b — ebuf dead before gemm1 runs, stream-ordered)
  float* dinv = (float*)d_ws;                          // n
  int*   offS = (int*)(dinv + n);                      // n
  int*   offE = offS + n;                              // n
  int*   gcur = offE + n;                              // NBUCK
  int*   srt  = gcur + NBUCK;                          // NBUCK*CAP
  ushort* xw1b = (ushort*)(srt + (size_t)NBUCK * CAP); // n*64 bf16
  int*   ebuf = (int*)xw1b;                            // NBUCK*CAP ints (10.5MB <= 12.8MB)
  ushort* hw2b = xw1b + (size_t)n * HID_C;             // n*32 bf16
  ushort* w1t_hi = hw2b + (size_t)n * OUT_C;           // 64*128
  ushort* w1t_lo = w1t_hi + HID_C * IN_C;              // 64*128

  int epb = (e + NBLK - 1) / NBLK;                     // 3125
  int nbuckets = (n + 255) / 256;                      // 391

  hipMemsetAsync(gcur, 0, NBUCK * sizeof(int), stream);
  hipLaunchKernelGGL(scatter_reserve_kernel, dim3(NBLK), dim3(256), 0, stream,
                     row, col, gcur, ebuf, e, epb);
  hipLaunchKernelGGL(csr_kernel, dim3(nbuckets), dim3(256), 0, stream,
                     ebuf, gcur, offS, offE, srt, dinv, n);
  hipLaunchKernelGGL(prep_w1t_kernel, dim3(1), dim3(256), 0, stream, W1, w1t_hi, w1t_lo);
  hipLaunchKernelGGL(gemm1_mfma_kernel, dim3((n + 63) / 64), dim3(256), 0, stream,
                     x, w1t_hi, w1t_lo, dinv, xw1b, n);
  hipLaunchKernelGGL(gather1_gemm2_kernel, dim3((n + 31) / 32), dim3(256), 0, stream,
                     offS, offE, srt, dinv, xw1b, b1, W2, hw2b, n);
  hipLaunchKernelGGL(gather2_kernel, dim3((n + 63) / 64), dim3(256), 0, stream,
                     offS, offE, srt, dinv, hw2b, b2, out, n);
}